// Round 1
// baseline (146.319 us; speedup 1.0000x reference)
//
#include <hip/hip_runtime.h>
#include <math.h>

#define B_BATCH 64
#define N_PTS   65536
#define BPB     32          // blocks per batch
#define THREADS 256

// ---------------------------------------------------------------------------
// Kernel 0: zero the accumulator (ws is poisoned 0xAA before every launch)
// ---------------------------------------------------------------------------
__global__ void zero_acc(float* __restrict__ acc) {
    int i = blockIdx.x * blockDim.x + threadIdx.x;
    if (i < B_BATCH * 16) acc[i] = 0.0f;
}

// ---------------------------------------------------------------------------
// Kernel 1: per-batch 16 weighted sums over N points.
//   acc[b][0]    = sum w
//   acc[b][1..3] = sum w*s_i          (A)
//   acc[b][4..6] = sum w*t_j          (B)
//   acc[b][7..15]= sum w*s_i*t_j      (S, row-major i*3+j)
// Layout: src/tgt are [B,3,N] (contiguous in n), w is [B,N].
// ---------------------------------------------------------------------------
__global__ __launch_bounds__(THREADS) void partial_sums(
        const float* __restrict__ src, const float* __restrict__ tgt,
        const float* __restrict__ w,  float* __restrict__ acc) {
    const int b   = blockIdx.x / BPB;
    const int blk = blockIdx.x % BPB;
    const int chunk = N_PTS / BPB;          // 2048 points per block
    const int n0 = blk * chunk;

    const float4* wp = (const float4*)(w   + (size_t)b * N_PTS          + n0);
    const float4* s0 = (const float4*)(src + ((size_t)b*3 + 0) * N_PTS + n0);
    const float4* s1 = (const float4*)(src + ((size_t)b*3 + 1) * N_PTS + n0);
    const float4* s2 = (const float4*)(src + ((size_t)b*3 + 2) * N_PTS + n0);
    const float4* t0 = (const float4*)(tgt + ((size_t)b*3 + 0) * N_PTS + n0);
    const float4* t1 = (const float4*)(tgt + ((size_t)b*3 + 1) * N_PTS + n0);
    const float4* t2 = (const float4*)(tgt + ((size_t)b*3 + 2) * N_PTS + n0);

    float a[16];
#pragma unroll
    for (int k = 0; k < 16; ++k) a[k] = 0.0f;

    const int nvec = chunk / 4;             // 512 float4 per block
    for (int i = threadIdx.x; i < nvec; i += THREADS) {
        float4 wv = wp[i];
        float4 x0 = s0[i], x1 = s1[i], x2 = s2[i];
        float4 y0 = t0[i], y1 = t1[i], y2 = t2[i];
#define ACC(C) { \
        float ww = wv.C; \
        float ws0 = ww * x0.C, ws1 = ww * x1.C, ws2 = ww * x2.C; \
        float yy0 = y0.C, yy1 = y1.C, yy2 = y2.C; \
        a[0]  += ww; \
        a[1]  += ws0;        a[2]  += ws1;        a[3]  += ws2; \
        a[4]  += ww * yy0;   a[5]  += ww * yy1;   a[6]  += ww * yy2; \
        a[7]  += ws0 * yy0;  a[8]  += ws0 * yy1;  a[9]  += ws0 * yy2; \
        a[10] += ws1 * yy0;  a[11] += ws1 * yy1;  a[12] += ws1 * yy2; \
        a[13] += ws2 * yy0;  a[14] += ws2 * yy1;  a[15] += ws2 * yy2; }
        ACC(x) ACC(y) ACC(z) ACC(w)
#undef ACC
    }

    // block reduction: wave64 shuffle tree, then LDS across the 4 waves
    const int lane = threadIdx.x & 63;
    const int wave = threadIdx.x >> 6;
    __shared__ float lds[4][16];
#pragma unroll
    for (int k = 0; k < 16; ++k) {
        float v = a[k];
        v += __shfl_down(v, 32);
        v += __shfl_down(v, 16);
        v += __shfl_down(v, 8);
        v += __shfl_down(v, 4);
        v += __shfl_down(v, 2);
        v += __shfl_down(v, 1);
        if (lane == 0) lds[wave][k] = v;
    }
    __syncthreads();
    if (threadIdx.x < 16) {
        float v = lds[0][threadIdx.x] + lds[1][threadIdx.x]
                + lds[2][threadIdx.x] + lds[3][threadIdx.x];
        atomicAdd(&acc[b * 16 + threadIdx.x], v);
    }
}

// ---------------------------------------------------------------------------
// Kernel 2: per-batch 3x3 Kabsch via fp64 Jacobi on H^T H. One thread/batch.
// ---------------------------------------------------------------------------
__global__ void finalize(const float* __restrict__ acc, float* __restrict__ out) {
    const int b = threadIdx.x;
    if (b >= B_BATCH) return;
    const float* p = acc + b * 16;

    double W = p[0];
    double A[3]  = {p[1], p[2], p[3]};
    double Bv[3] = {p[4], p[5], p[6]};
    double H[3][3];
#pragma unroll
    for (int i = 0; i < 3; ++i)
#pragma unroll
        for (int j = 0; j < 3; ++j)
            H[i][j] = (double)p[7 + i*3 + j] + (W - 2.0) * A[i] * Bv[j];

    // scale-normalize H (R is scale-invariant); guards denormals
    double fn = 0.0;
    for (int i = 0; i < 3; ++i) for (int j = 0; j < 3; ++j) fn += H[i][j]*H[i][j];
    fn = sqrt(fn);
    double inv = (fn > 1e-300) ? 1.0/fn : 1.0;
    double h[3][3];
    for (int i = 0; i < 3; ++i) for (int j = 0; j < 3; ++j) h[i][j] = H[i][j]*inv;

    // M = h^T h (symmetric PSD)
    double M[3][3];
    for (int i = 0; i < 3; ++i)
        for (int j = 0; j < 3; ++j) {
            double s = 0.0;
            for (int k = 0; k < 3; ++k) s += h[k][i] * h[k][j];
            M[i][j] = s;
        }

    // cyclic Jacobi eigendecomposition: M = V diag(e) V^T
    double V[3][3] = {{1,0,0},{0,1,0},{0,0,1}};
    const int PAIRS[3][2] = {{0,1},{0,2},{1,2}};
    for (int sweep = 0; sweep < 20; ++sweep) {
        double off = M[0][1]*M[0][1] + M[0][2]*M[0][2] + M[1][2]*M[1][2];
        if (off < 1e-32) break;
        for (int pp = 0; pp < 3; ++pp) {
            const int pq = PAIRS[pp][0], qq = PAIRS[pp][1];
            double apq = M[pq][qq];
            if (fabs(apq) < 1e-300) continue;
            double tau = (M[qq][qq] - M[pq][pq]) / (2.0 * apq);
            double t = (tau >= 0.0 ? 1.0 : -1.0) / (fabs(tau) + sqrt(1.0 + tau*tau));
            double c = 1.0 / sqrt(1.0 + t*t), s = t * c;
            for (int k = 0; k < 3; ++k) {           // M <- M J (columns p,q)
                double mkp = M[k][pq], mkq = M[k][qq];
                M[k][pq] = c*mkp - s*mkq;
                M[k][qq] = s*mkp + c*mkq;
            }
            for (int k = 0; k < 3; ++k) {           // M <- J^T M (rows p,q)
                double mpk = M[pq][k], mqk = M[qq][k];
                M[pq][k] = c*mpk - s*mqk;
                M[qq][k] = s*mpk + c*mqk;
            }
            for (int k = 0; k < 3; ++k) {           // V <- V J
                double vkp = V[k][pq], vkq = V[k][qq];
                V[k][pq] = c*vkp - s*vkq;
                V[k][qq] = s*vkp + c*vkq;
            }
        }
    }

    // sort eigenvalues descending -> column permutation of V
    double e[3] = {M[0][0], M[1][1], M[2][2]};
    int idx[3] = {0, 1, 2};
    if (e[idx[0]] < e[idx[1]]) { int t_ = idx[0]; idx[0] = idx[1]; idx[1] = t_; }
    if (e[idx[0]] < e[idx[2]]) { int t_ = idx[0]; idx[0] = idx[2]; idx[2] = t_; }
    if (e[idx[1]] < e[idx[2]]) { int t_ = idx[1]; idx[1] = idx[2]; idx[2] = t_; }
    double Vc[3][3];
    for (int i = 0; i < 3; ++i)
        for (int k = 0; k < 3; ++k) Vc[i][k] = V[i][idx[k]];

    // U columns: u_k = h * v_k / sigma_k ; u3 = u1 x u2 (orthonormal completion)
    double u[3][3];   // u[k][j] = component j of left singular vector k
    double hv[3][3];  // hv[k][j] = (h * v_k)_j
    for (int k = 0; k < 3; ++k)
        for (int j = 0; j < 3; ++j) {
            double s = 0.0;
            for (int m = 0; m < 3; ++m) s += h[j][m] * Vc[m][k];
            hv[k][j] = s;
        }
    // u1
    double n1 = sqrt(hv[0][0]*hv[0][0] + hv[0][1]*hv[0][1] + hv[0][2]*hv[0][2]);
    double in1 = (n1 > 1e-150) ? 1.0/n1 : 0.0;
    for (int j = 0; j < 3; ++j) u[0][j] = hv[0][j] * in1;
    if (in1 == 0.0) { u[0][0] = 1.0; u[0][1] = 0.0; u[0][2] = 0.0; }
    // u2: orthogonalize hv2 against u1
    double d12 = u[0][0]*hv[1][0] + u[0][1]*hv[1][1] + u[0][2]*hv[1][2];
    double w2[3];
    for (int j = 0; j < 3; ++j) w2[j] = hv[1][j] - d12 * u[0][j];
    double n2 = sqrt(w2[0]*w2[0] + w2[1]*w2[1] + w2[2]*w2[2]);
    if (n2 > 1e-150) {
        for (int j = 0; j < 3; ++j) u[1][j] = w2[j] / n2;
    } else {
        // any unit vector orthogonal to u1
        double ax = fabs(u[0][0]), ay = fabs(u[0][1]), az = fabs(u[0][2]);
        double t2[3];
        if (ax <= ay && ax <= az)      { t2[0]=0; t2[1]=-u[0][2]; t2[2]=u[0][1]; }
        else if (ay <= az)             { t2[0]=-u[0][2]; t2[1]=0; t2[2]=u[0][0]; }
        else                           { t2[0]=-u[0][1]; t2[1]=u[0][0]; t2[2]=0; }
        double nt = sqrt(t2[0]*t2[0] + t2[1]*t2[1] + t2[2]*t2[2]);
        for (int j = 0; j < 3; ++j) u[1][j] = t2[j] / nt;
    }
    // u3 = u1 x u2
    u[2][0] = u[0][1]*u[1][2] - u[0][2]*u[1][1];
    u[2][1] = u[0][2]*u[1][0] - u[0][0]*u[1][2];
    u[2][2] = u[0][0]*u[1][1] - u[0][1]*u[1][0];

    // R0 = V U^T ; det fix flips 3rd column of V
    double R[3][3];
    for (int i = 0; i < 3; ++i)
        for (int j = 0; j < 3; ++j) {
            double s = 0.0;
            for (int k = 0; k < 3; ++k) s += Vc[i][k] * u[k][j];
            R[i][j] = s;
        }
    double det = R[0][0]*(R[1][1]*R[2][2] - R[1][2]*R[2][1])
               - R[0][1]*(R[1][0]*R[2][2] - R[1][2]*R[2][0])
               + R[0][2]*(R[1][0]*R[2][1] - R[1][1]*R[2][0]);
    if (det < 0.0)
        for (int i = 0; i < 3; ++i)
            for (int j = 0; j < 3; ++j)
                R[i][j] -= 2.0 * Vc[i][2] * u[2][j];

    // t = tgtm - R @ srcm
    double tv[3];
    for (int i = 0; i < 3; ++i)
        tv[i] = Bv[i] - (R[i][0]*A[0] + R[i][1]*A[1] + R[i][2]*A[2]);

    // outputs: R [64,3,3] then t [64,3], concatenated flat
    for (int i = 0; i < 3; ++i)
        for (int j = 0; j < 3; ++j)
            out[b*9 + i*3 + j] = (float)R[i][j];
    for (int i = 0; i < 3; ++i)
        out[B_BATCH*9 + b*3 + i] = (float)tv[i];
}

// ---------------------------------------------------------------------------
extern "C" void kernel_launch(void* const* d_in, const int* in_sizes, int n_in,
                              void* d_out, int out_size, void* d_ws, size_t ws_size,
                              hipStream_t stream) {
    const float* src = (const float*)d_in[0];
    const float* tgt = (const float*)d_in[1];
    const float* w   = (const float*)d_in[2];
    float* out = (float*)d_out;
    float* acc = (float*)d_ws;    // 64*16 floats = 4 KB

    zero_acc<<<(B_BATCH*16 + 255)/256, 256, 0, stream>>>(acc);
    partial_sums<<<B_BATCH * BPB, THREADS, 0, stream>>>(src, tgt, w, acc);
    finalize<<<1, 64, 0, stream>>>(acc, out);
}